// Round 13
// baseline (137103.320 us; speedup 1.0000x reference)
//
#include <hip/hip_runtime.h>
#include <math.h>

// Problem constants
#define BATCH   8192
#define EXP_DIM 1024
#define DICT    4096
#define NIT     20
#define KSP     409
#define STEP_F  0.1f
#define THR_F   0.01f

__device__ __forceinline__ float soft_update(float oldv, float g) {
    float a = oldv + STEP_F * g;
    float m = fabsf(a) - THR_F;
    return m > 0.0f ? copysignf(m, a) : 0.0f;
}

// ---------------------------------------------------------------------------
// One-time: DT[n][k] = D[k][n].  D:[4096,1024] -> DT:[1024,4096].
__global__ __launch_bounds__(256)
void transpose_d(const float* __restrict__ D, float* __restrict__ DT) {
    __shared__ float tile[32][33];
    const int t = threadIdx.x;
    const int tx = t & 31, ty = t >> 5;          // 32 x 8
    const int n0 = blockIdx.x * 32;              // EXP_DIM block
    const int k0 = blockIdx.y * 32;              // DICT block
#pragma unroll
    for (int i = 0; i < 4; ++i)
        tile[ty + 8 * i][tx] = D[(size_t)(k0 + ty + 8 * i) * EXP_DIM + n0 + tx];
    __syncthreads();
#pragma unroll
    for (int i = 0; i < 4; ++i)
        DT[(size_t)(n0 + ty + 8 * i) * DICT + k0 + tx] = tile[tx][ty + 8 * i];
}

// ---------------------------------------------------------------------------
// GEMM1 (register-streamed A + LDS B):  R = X - A*DT^T.
// C[m][n] = sum_k A[m][k]*DT[n][k], k strictly ascending per output
// (FMA chain bit-identical to rounds 0/7/8/9/12 -> absmax stays 0.0078125).
// Tile 128(M)x64(N), 256 thr, 8x4/thread. Per k: 1 ds_read_b128 + 32 FMA
// (32:1, LDS 2x headroom) + 2 global loads (A, reg-double-buffered by 4-k
// groups; loads never wait on barriers). Grid 16x64=1024 = 4 blk/CU.
#define G1_TK 16

__global__ __launch_bounds__(256, 4)
void gemm1_rs(const float* __restrict__ Asrc, const float* __restrict__ DT,
              const float* __restrict__ X, float* __restrict__ R) {
    __shared__ float Bs[G1_TK][68];              // [k][n], +4 pad
    const int t = threadIdx.x;
    const int tx = t & 15, ty = t >> 4;          // tx: 4 cols, ty: 8 rows

    // XCD remap: all 16 col-blocks of one A row-panel -> same XCD, consecutive
    const int lin = blockIdx.y * 16 + blockIdx.x;    // 0..1023
    const int xcd = lin & 7, j = lin >> 3;           // j 0..127
    const int row0 = (xcd * 8 + (j >> 4)) * 128;     // 64 row-panels
    const int col0 = (j & 15) * 64;                  // 16 col-tiles

    const float* pA[8];
#pragma unroll
    for (int r = 0; r < 8; ++r)
        pA[r] = Asrc + (size_t)(row0 + ty * 8 + r) * DICT;

    // B stage: thread t loads DT[(col0 + (t&63))][k0 + (t>>6)*4 ..+3]
    const int bn = t & 63, bk4 = (t >> 6) << 2;
    const float* pB = DT + (size_t)(col0 + bn) * DICT + bk4;

    float acc[8][4] = {};
    float4 a_reg[2][8];

#pragma unroll
    for (int r = 0; r < 8; ++r) a_reg[0][r] = *(const float4*)(pA[r]);

    for (int k0 = 0; k0 < DICT; k0 += G1_TK) {
        __syncthreads();                         // previous Bs fully consumed
        {
            float4 b = *(const float4*)(pB + k0);
            Bs[bk4 + 0][bn] = b.x;
            Bs[bk4 + 1][bn] = b.y;
            Bs[bk4 + 2][bn] = b.z;
            Bs[bk4 + 3][bn] = b.w;
        }
        __syncthreads();
#pragma unroll
        for (int g = 0; g < 4; ++g) {            // 4-k groups; cur/nxt alternate
            const int kb = k0 + g * 4;
            const int cur = g & 1, nxt = cur ^ 1;
            if (kb + 4 < DICT) {                 // uniform branch; prefetch next
#pragma unroll
                for (int r = 0; r < 8; ++r)
                    a_reg[nxt][r] = *(const float4*)(pA[r] + kb + 4);
            }
#pragma unroll
            for (int kk = 0; kk < 4; ++kk) {
                float4 bv = *(const float4*)&Bs[g * 4 + kk][tx * 4];
                const float bvr[4] = {bv.x, bv.y, bv.z, bv.w};
#pragma unroll
                for (int r = 0; r < 8; ++r) {
                    const float a = (kk == 0) ? a_reg[cur][r].x
                                  : (kk == 1) ? a_reg[cur][r].y
                                  : (kk == 2) ? a_reg[cur][r].z
                                              : a_reg[cur][r].w;
                    acc[r][0] += a * bvr[0];
                    acc[r][1] += a * bvr[1];
                    acc[r][2] += a * bvr[2];
                    acc[r][3] += a * bvr[3];
                }
            }
        }
        // 4 groups (even) -> a_reg[0] holds next stage's group 0
    }

#pragma unroll
    for (int r = 0; r < 8; ++r) {
        const size_t off = (size_t)(row0 + ty * 8 + r) * EXP_DIM + col0 + tx * 4;
        float4 xv = *(const float4*)&X[off];
        float4 o;
        o.x = xv.x - acc[r][0]; o.y = xv.y - acc[r][1];
        o.z = xv.z - acc[r][2]; o.w = xv.w - acc[r][3];
        *(float4*)&R[off] = o;
    }
}

// ---------------------------------------------------------------------------
// GEMM2: A = soft(A + STEP * R*D^T) — byte-identical to rounds 7/8/9/12
// (measured ~83% of fp32 vector peak; do not touch).
#define TK 16
#define LDS_LD 132

__global__ __launch_bounds__(256)
void gemm2_update(const float* __restrict__ Rsrc, const float* __restrict__ D,
                  float* __restrict__ Aa) {
    __shared__ float AsT[TK][LDS_LD];
    __shared__ float BsT[TK][LDS_LD];
    const int t  = threadIdx.x;
    const int tx = t & 15, ty = t >> 4;
    const int row0 = blockIdx.y * 128, col0 = blockIdx.x * 128;

    const int arow = t >> 1, akg = (t & 1) << 3;
    const float* pA = Rsrc + (size_t)(row0 + arow) * EXP_DIM + akg;
    const float* pB = D + (size_t)(col0 + arow) * EXP_DIM + akg;

    float acc[8][8] = {};

    for (int k0 = 0; k0 < EXP_DIM; k0 += TK) {
        float4 a0 = *(const float4*)(pA + k0);
        float4 a1 = *(const float4*)(pA + k0 + 4);
        float4 b0 = *(const float4*)(pB + k0);
        float4 b1 = *(const float4*)(pB + k0 + 4);
        __syncthreads();
        AsT[akg + 0][arow] = a0.x; AsT[akg + 1][arow] = a0.y;
        AsT[akg + 2][arow] = a0.z; AsT[akg + 3][arow] = a0.w;
        AsT[akg + 4][arow] = a1.x; AsT[akg + 5][arow] = a1.y;
        AsT[akg + 6][arow] = a1.z; AsT[akg + 7][arow] = a1.w;
        BsT[akg + 0][arow] = b0.x; BsT[akg + 1][arow] = b0.y;
        BsT[akg + 2][arow] = b0.z; BsT[akg + 3][arow] = b0.w;
        BsT[akg + 4][arow] = b1.x; BsT[akg + 5][arow] = b1.y;
        BsT[akg + 6][arow] = b1.z; BsT[akg + 7][arow] = b1.w;
        __syncthreads();
#pragma unroll
        for (int k = 0; k < TK; ++k) {
            float4 av0 = *(const float4*)&AsT[k][ty * 4];
            float4 av1 = *(const float4*)&AsT[k][64 + ty * 4];
            float4 bv0 = *(const float4*)&BsT[k][tx * 4];
            float4 bv1 = *(const float4*)&BsT[k][64 + tx * 4];
            float av[8] = {av0.x, av0.y, av0.z, av0.w, av1.x, av1.y, av1.z, av1.w};
            float bv[8] = {bv0.x, bv0.y, bv0.z, bv0.w, bv1.x, bv1.y, bv1.z, bv1.w};
#pragma unroll
            for (int i = 0; i < 8; ++i)
#pragma unroll
                for (int jj = 0; jj < 8; ++jj)
                    acc[i][jj] += av[i] * bv[jj];
        }
    }

#pragma unroll
    for (int i = 0; i < 8; ++i) {
        const int r = row0 + ((i < 4) ? (ty * 4 + i) : (64 + ty * 4 + i - 4));
        {
            float4* p = (float4*)&Aa[(size_t)r * DICT + col0 + tx * 4];
            float4 oldv = *p;
            float4 o;
            o.x = soft_update(oldv.x, acc[i][0]);
            o.y = soft_update(oldv.y, acc[i][1]);
            o.z = soft_update(oldv.z, acc[i][2]);
            o.w = soft_update(oldv.w, acc[i][3]);
            *p = o;
        }
        {
            float4* p = (float4*)&Aa[(size_t)r * DICT + col0 + 64 + tx * 4];
            float4 oldv = *p;
            float4 o;
            o.x = soft_update(oldv.x, acc[i][4]);
            o.y = soft_update(oldv.y, acc[i][5]);
            o.z = soft_update(oldv.z, acc[i][6]);
            o.w = soft_update(oldv.w, acc[i][7]);
            *p = o;
        }
    }
}

// ---------------------------------------------------------------------------
// fp32 GEMM1 fallback (only if ws too small for DT) — verified round-0 kernel.
#define BM  64
#define BN  64
#define BK  16
#define LDT 68

__global__ __launch_bounds__(256)
void gemm1_resid(const float* __restrict__ A, const float* __restrict__ D,
                 const float* __restrict__ X, float* __restrict__ R) {
    __shared__ float As[BK][LDT];
    __shared__ float Bs[BK][LDT];
    const int t    = threadIdx.x;
    const int row0 = blockIdx.y * BM;
    const int col0 = blockIdx.x * BN;
    const int tx = t & 15, ty = t >> 4;
    const int lr = t >> 2;
    const int lk = (t & 3) << 2;
    const int bkr = t >> 4;
    const int bn  = (t & 15) << 2;

    float acc[4][4] = {};

    for (int k0 = 0; k0 < DICT; k0 += BK) {
        float4 av = *(const float4*)&A[(row0 + lr) * DICT + k0 + lk];
        float4 bv = *(const float4*)&D[(k0 + bkr) * EXP_DIM + col0 + bn];
        __syncthreads();
        As[lk + 0][lr] = av.x; As[lk + 1][lr] = av.y;
        As[lk + 2][lr] = av.z; As[lk + 3][lr] = av.w;
        *(float4*)&Bs[bkr][bn] = bv;
        __syncthreads();
#pragma unroll
        for (int k = 0; k < BK; ++k) {
            float4 a = *(const float4*)&As[k][ty << 2];
            float4 b = *(const float4*)&Bs[k][tx << 2];
            float avr[4] = {a.x, a.y, a.z, a.w};
            float bvr[4] = {b.x, b.y, b.z, b.w};
#pragma unroll
            for (int i = 0; i < 4; ++i)
#pragma unroll
                for (int j = 0; j < 4; ++j)
                    acc[i][j] += avr[i] * bvr[j];
        }
    }

#pragma unroll
    for (int i = 0; i < 4; ++i) {
        int r = row0 + (ty << 2) + i;
        int c = col0 + (tx << 2);
        float4 xv = *(const float4*)&X[r * EXP_DIM + c];
        float4 o;
        o.x = xv.x - acc[i][0];
        o.y = xv.y - acc[i][1];
        o.z = xv.z - acc[i][2];
        o.w = xv.w - acc[i][3];
        *(float4*)&R[r * EXP_DIM + c] = o;
    }
}

// ---------------------------------------------------------------------------
// In-place top-KSP by |value| per row (exact MSB-first radix select; verified).
__global__ __launch_bounds__(256)
void topk_kernel(float* __restrict__ A) {
    const int row = blockIdx.x;
    float* a = A + (size_t)row * DICT;
    __shared__ unsigned int sb[DICT];
    __shared__ unsigned int hist[256];
    __shared__ unsigned int s_bin, s_need;
    const int t = threadIdx.x;

#pragma unroll
    for (int i = 0; i < DICT / 256; ++i) {
        int j = t + 256 * i;
        sb[j] = __float_as_uint(a[j]) & 0x7fffffffu;
    }

    unsigned int prefix = 0, needed = KSP;
    for (int shift = 24; shift >= 0; shift -= 8) {
        __syncthreads();
        hist[t] = 0;
        __syncthreads();
        unsigned int hmask = (shift == 24) ? 0u : (0xffffffffu << (shift + 8));
        for (int i = 0; i < DICT / 256; ++i) {
            unsigned int b = sb[t + 256 * i];
            if ((b & hmask) == prefix)
                atomicAdd(&hist[(b >> shift) & 0xffu], 1u);
        }
        __syncthreads();
        if (t == 0) {
            unsigned int cum = 0;
            for (int bin = 255; bin >= 0; --bin) {
                unsigned int h = hist[bin];
                if (cum + h >= needed) { s_bin = (unsigned int)bin; s_need = needed - cum; break; }
                cum += h;
            }
        }
        __syncthreads();
        prefix |= s_bin << shift;
        needed = s_need;
    }

    unsigned int E = hist[prefix & 0xffu];
    bool simple = (E == needed) || (prefix == 0);
    if (!simple) {
        if (t == 0) {
            unsigned int cnt = 0;
            for (int j = 0; j < DICT; ++j) {
                if (sb[j] == prefix) {
                    if (cnt < needed) sb[j] |= 0x80000000u;
                    ++cnt;
                }
            }
        }
        __syncthreads();
    }

    for (int i = 0; i < DICT / 256; ++i) {
        int j = t + 256 * i;
        unsigned int b = sb[j];
        bool keep = simple ? (b >= prefix)
                           : (((b & 0x7fffffffu) > prefix) || (b >> 31));
        float v = a[j];
        a[j] = keep ? v : 0.0f;
    }
}

// ---------------------------------------------------------------------------
extern "C" void kernel_launch(void* const* d_in, const int* in_sizes, int n_in,
                              void* d_out, int out_size, void* d_ws, size_t ws_size,
                              hipStream_t stream) {
    const float* X = (const float*)d_in[0];   // [8192,1024]
    const float* D = (const float*)d_in[1];   // [4096,1024]
    float* A = (float*)d_out;                 // [8192,4096] alpha, iterated in place

    const size_t R_ELEMS  = (size_t)BATCH * EXP_DIM;     // 8.4M floats, 33.5 MB
    const size_t DT_ELEMS = (size_t)EXP_DIM * DICT;      // 4.2M floats, 16.8 MB
    const size_t NEED = (R_ELEMS + DT_ELEMS) * sizeof(float);  // 50.3 MB

    hipMemsetAsync(A, 0, (size_t)BATCH * DICT * sizeof(float), stream);

    dim3 blk(256);
    dim3 g2(DICT / 128, BATCH / 128);     // 32 x 64 = 2048 blocks

    if (ws_size >= NEED) {
        float* R  = (float*)d_ws;
        float* DT = R + R_ELEMS;          // [1024][4096]

        hipLaunchKernelGGL(transpose_d, dim3(EXP_DIM / 32, DICT / 32), blk, 0,
                           stream, D, DT);

        dim3 g1(16, 64);                  // 1024 blocks (4/CU)
        for (int it = 0; it < NIT; ++it) {
            // iter 0: A==0 -> R = X exactly (matches reference's first step)
            hipLaunchKernelGGL(gemm1_rs, g1, blk, 0, stream, A, DT, X, R);
            hipLaunchKernelGGL(gemm2_update, g2, blk, 0, stream, R, D, A);
        }
    } else {
        float* R = (float*)d_ws;
        dim3 og1(EXP_DIM / BN, BATCH / BM);
        for (int it = 0; it < NIT; ++it) {
            hipLaunchKernelGGL(gemm1_resid, og1, blk, 0, stream, A, D, X, R);
            hipLaunchKernelGGL(gemm2_update, g2, blk, 0, stream, R, D, A);
        }
    }
    hipLaunchKernelGGL(topk_kernel, dim3(BATCH), blk, 0, stream, A);
}

// Round 14
// 36243.915 us; speedup vs baseline: 3.7828x; 3.7828x over previous
//
#include <hip/hip_runtime.h>
#include <math.h>

// Problem constants
#define BATCH   8192
#define EXP_DIM 1024
#define DICT    4096
#define NIT     20
#define KSP     409
#define STEP_F  0.1f
#define THR_F   0.01f

// 128x128 block tile, TK=16, 256 threads, 8x8 outputs per thread.
// Per-output summation is k strictly ascending, single fp32 accumulator
// (bit-identical trajectory to the verified rounds 0/7/8/9).
#define TK 16
#define LDS_LD 132

__device__ __forceinline__ float soft_update(float oldv, float g) {
    float a = oldv + STEP_F * g;
    float m = fabsf(a) - THR_F;
    return m > 0.0f ? copysignf(m, a) : 0.0f;
}

// ---------------------------------------------------------------------------
// GEMM1: R = X - A*D.  A:[BATCH,DICT]  D:[DICT,EXP_DIM]  X,R:[BATCH,EXP_DIM]
// (byte-identical to round 7's verified kernel — 990 us, best measured total)
__global__ __launch_bounds__(256)
void gemm1_resid(const float* __restrict__ A, const float* __restrict__ D,
                 const float* __restrict__ X, float* __restrict__ R) {
    __shared__ float AsT[TK][LDS_LD];   // transposed A tile: [k][row]
    __shared__ float Bs [TK][LDS_LD];   // D tile straight:  [k][col]
    const int t  = threadIdx.x;
    const int tx = t & 15, ty = t >> 4;
    const int row0 = blockIdx.y * 128, col0 = blockIdx.x * 128;

    // A staging: thread t owns (row = t>>1, k-group = (t&1)*8)
    const int arow = t >> 1, akg = (t & 1) << 3;
    const float* pA = A + (size_t)(row0 + arow) * DICT + akg;
    // B staging: thread t owns (k-row = t>>4, col-group = (t&15)*8)
    const int bkr = t >> 4, bcg = (t & 15) << 3;
    const float* pB = D + (size_t)bkr * EXP_DIM + col0 + bcg;

    float acc[8][8] = {};

    for (int k0 = 0; k0 < DICT; k0 += TK) {
        float4 a0 = *(const float4*)(pA + k0);
        float4 a1 = *(const float4*)(pA + k0 + 4);
        float4 b0 = *(const float4*)(pB + (size_t)k0 * EXP_DIM);
        float4 b1 = *(const float4*)(pB + (size_t)k0 * EXP_DIM + 4);
        __syncthreads();
        AsT[akg + 0][arow] = a0.x; AsT[akg + 1][arow] = a0.y;
        AsT[akg + 2][arow] = a0.z; AsT[akg + 3][arow] = a0.w;
        AsT[akg + 4][arow] = a1.x; AsT[akg + 5][arow] = a1.y;
        AsT[akg + 6][arow] = a1.z; AsT[akg + 7][arow] = a1.w;
        *(float4*)&Bs[bkr][bcg]     = b0;
        *(float4*)&Bs[bkr][bcg + 4] = b1;
        __syncthreads();
#pragma unroll
        for (int k = 0; k < TK; ++k) {
            float4 av0 = *(const float4*)&AsT[k][ty * 4];
            float4 av1 = *(const float4*)&AsT[k][64 + ty * 4];
            float4 bv0 = *(const float4*)&Bs[k][tx * 4];
            float4 bv1 = *(const float4*)&Bs[k][64 + tx * 4];
            float av[8] = {av0.x, av0.y, av0.z, av0.w, av1.x, av1.y, av1.z, av1.w};
            float bv[8] = {bv0.x, bv0.y, bv0.z, bv0.w, bv1.x, bv1.y, bv1.z, bv1.w};
#pragma unroll
            for (int i = 0; i < 8; ++i)
#pragma unroll
                for (int j = 0; j < 8; ++j)
                    acc[i][j] += av[i] * bv[j];
        }
    }

#pragma unroll
    for (int i = 0; i < 8; ++i) {
        const int r = row0 + ((i < 4) ? (ty * 4 + i) : (64 + ty * 4 + i - 4));
        {
            const size_t off = (size_t)r * EXP_DIM + col0 + tx * 4;
            float4 xv = *(const float4*)&X[off];
            float4 o;
            o.x = xv.x - acc[i][0]; o.y = xv.y - acc[i][1];
            o.z = xv.z - acc[i][2]; o.w = xv.w - acc[i][3];
            *(float4*)&R[off] = o;
        }
        {
            const size_t off = (size_t)r * EXP_DIM + col0 + 64 + tx * 4;
            float4 xv = *(const float4*)&X[off];
            float4 o;
            o.x = xv.x - acc[i][4]; o.y = xv.y - acc[i][5];
            o.z = xv.z - acc[i][6]; o.w = xv.w - acc[i][7];
            *(float4*)&R[off] = o;
        }
    }
}

// ---------------------------------------------------------------------------
// GEMM2: A = soft(A + STEP * R*D^T).  R:[BATCH,EXP_DIM]  D:[DICT,EXP_DIM]
// (byte-identical to rounds 7/8/9/12 — measured ~83% of fp32 vector peak)
__global__ __launch_bounds__(256)
void gemm2_update(const float* __restrict__ Rsrc, const float* __restrict__ D,
                  float* __restrict__ Aa) {
    __shared__ float AsT[TK][LDS_LD];   // transposed R tile: [k][row]
    __shared__ float BsT[TK][LDS_LD];   // transposed D tile: [k][n]
    const int t  = threadIdx.x;
    const int tx = t & 15, ty = t >> 4;
    const int row0 = blockIdx.y * 128, col0 = blockIdx.x * 128;

    const int arow = t >> 1, akg = (t & 1) << 3;
    const float* pA = Rsrc + (size_t)(row0 + arow) * EXP_DIM + akg;
    const float* pB = D + (size_t)(col0 + arow) * EXP_DIM + akg;

    float acc[8][8] = {};

    for (int k0 = 0; k0 < EXP_DIM; k0 += TK) {
        float4 a0 = *(const float4*)(pA + k0);
        float4 a1 = *(const float4*)(pA + k0 + 4);
        float4 b0 = *(const float4*)(pB + k0);
        float4 b1 = *(const float4*)(pB + k0 + 4);
        __syncthreads();
        AsT[akg + 0][arow] = a0.x; AsT[akg + 1][arow] = a0.y;
        AsT[akg + 2][arow] = a0.z; AsT[akg + 3][arow] = a0.w;
        AsT[akg + 4][arow] = a1.x; AsT[akg + 5][arow] = a1.y;
        AsT[akg + 6][arow] = a1.z; AsT[akg + 7][arow] = a1.w;
        BsT[akg + 0][arow] = b0.x; BsT[akg + 1][arow] = b0.y;
        BsT[akg + 2][arow] = b0.z; BsT[akg + 3][arow] = b0.w;
        BsT[akg + 4][arow] = b1.x; BsT[akg + 5][arow] = b1.y;
        BsT[akg + 6][arow] = b1.z; BsT[akg + 7][arow] = b1.w;
        __syncthreads();
#pragma unroll
        for (int k = 0; k < TK; ++k) {
            float4 av0 = *(const float4*)&AsT[k][ty * 4];
            float4 av1 = *(const float4*)&AsT[k][64 + ty * 4];
            float4 bv0 = *(const float4*)&BsT[k][tx * 4];
            float4 bv1 = *(const float4*)&BsT[k][64 + tx * 4];
            float av[8] = {av0.x, av0.y, av0.z, av0.w, av1.x, av1.y, av1.z, av1.w};
            float bv[8] = {bv0.x, bv0.y, bv0.z, bv0.w, bv1.x, bv1.y, bv1.z, bv1.w};
#pragma unroll
            for (int i = 0; i < 8; ++i)
#pragma unroll
                for (int j = 0; j < 8; ++j)
                    acc[i][j] += av[i] * bv[j];
        }
    }

#pragma unroll
    for (int i = 0; i < 8; ++i) {
        const int r = row0 + ((i < 4) ? (ty * 4 + i) : (64 + ty * 4 + i - 4));
        {
            float4* p = (float4*)&Aa[(size_t)r * DICT + col0 + tx * 4];
            float4 oldv = *p;
            float4 o;
            o.x = soft_update(oldv.x, acc[i][0]);
            o.y = soft_update(oldv.y, acc[i][1]);
            o.z = soft_update(oldv.z, acc[i][2]);
            o.w = soft_update(oldv.w, acc[i][3]);
            *p = o;
        }
        {
            float4* p = (float4*)&Aa[(size_t)r * DICT + col0 + 64 + tx * 4];
            float4 oldv = *p;
            float4 o;
            o.x = soft_update(oldv.x, acc[i][4]);
            o.y = soft_update(oldv.y, acc[i][5]);
            o.z = soft_update(oldv.z, acc[i][6]);
            o.w = soft_update(oldv.w, acc[i][7]);
            *p = o;
        }
    }
}

// ---------------------------------------------------------------------------
// In-place top-KSP by |value| per row (exact MSB-first radix select; verified).
__global__ __launch_bounds__(256)
void topk_kernel(float* __restrict__ A) {
    const int row = blockIdx.x;
    float* a = A + (size_t)row * DICT;
    __shared__ unsigned int sb[DICT];
    __shared__ unsigned int hist[256];
    __shared__ unsigned int s_bin, s_need;
    const int t = threadIdx.x;

#pragma unroll
    for (int i = 0; i < DICT / 256; ++i) {
        int j = t + 256 * i;
        sb[j] = __float_as_uint(a[j]) & 0x7fffffffu;
    }

    unsigned int prefix = 0, needed = KSP;
    for (int shift = 24; shift >= 0; shift -= 8) {
        __syncthreads();
        hist[t] = 0;
        __syncthreads();
        unsigned int hmask = (shift == 24) ? 0u : (0xffffffffu << (shift + 8));
        for (int i = 0; i < DICT / 256; ++i) {
            unsigned int b = sb[t + 256 * i];
            if ((b & hmask) == prefix)
                atomicAdd(&hist[(b >> shift) & 0xffu], 1u);
        }
        __syncthreads();
        if (t == 0) {
            unsigned int cum = 0;
            for (int bin = 255; bin >= 0; --bin) {
                unsigned int h = hist[bin];
                if (cum + h >= needed) { s_bin = (unsigned int)bin; s_need = needed - cum; break; }
                cum += h;
            }
        }
        __syncthreads();
        prefix |= s_bin << shift;
        needed = s_need;
    }

    unsigned int E = hist[prefix & 0xffu];
    bool simple = (E == needed) || (prefix == 0);
    if (!simple) {
        if (t == 0) {
            unsigned int cnt = 0;
            for (int j = 0; j < DICT; ++j) {
                if (sb[j] == prefix) {
                    if (cnt < needed) sb[j] |= 0x80000000u;
                    ++cnt;
                }
            }
        }
        __syncthreads();
    }

    for (int i = 0; i < DICT / 256; ++i) {
        int j = t + 256 * i;
        unsigned int b = sb[j];
        bool keep = simple ? (b >= prefix)
                           : (((b & 0x7fffffffu) > prefix) || (b >> 31));
        float v = a[j];
        a[j] = keep ? v : 0.0f;
    }
}

// ---------------------------------------------------------------------------
extern "C" void kernel_launch(void* const* d_in, const int* in_sizes, int n_in,
                              void* d_out, int out_size, void* d_ws, size_t ws_size,
                              hipStream_t stream) {
    const float* X = (const float*)d_in[0];   // [8192,1024]
    const float* D = (const float*)d_in[1];   // [4096,1024]
    float* A = (float*)d_out;                 // [8192,4096] alpha, iterated in place
    float* R = (float*)d_ws;                  // [8192,1024] residual scratch (33.5 MB)

    hipMemsetAsync(A, 0, (size_t)BATCH * DICT * sizeof(float), stream);

    dim3 blk(256);
    dim3 g1(EXP_DIM / 128, BATCH / 128);  // 8 x 64 = 512 blocks
    dim3 g2(DICT / 128,    BATCH / 128);  // 32 x 64 = 2048 blocks

    // Iteration 0: A == 0 (memset), so gemm1 would compute R = X - 0 = X
    // bitwise. Skip it and feed X directly to gemm2 — trajectory-identical,
    // saves one full gemm1 dispatch (~990 us).
    hipLaunchKernelGGL(gemm2_update, g2, blk, 0, stream, X, D, A);
    for (int it = 1; it < NIT; ++it) {
        hipLaunchKernelGGL(gemm1_resid, g1, blk, 0, stream, A, D, X, R);
        hipLaunchKernelGGL(gemm2_update, g2, blk, 0, stream, R, D, A);
    }
    hipLaunchKernelGGL(topk_kernel, dim3(BATCH), blk, 0, stream, A);
}

// Round 15
// 30025.314 us; speedup vs baseline: 4.5663x; 1.2071x over previous
//
#include <hip/hip_runtime.h>
#include <math.h>

// Problem constants
#define BATCH   8192
#define EXP_DIM 1024
#define DICT    4096
#define NIT     20
#define KSP     409
#define STEP_F  0.1f
#define THR_F   0.01f

// 128x128 block tile, TK=16, 256 threads, 8x8 outputs per thread.
// Per-output summation is k strictly ascending, single fp32 accumulator
// (bit-identical trajectory to the verified rounds 0/7/8/9/14).
// NOTE (hard invariant): the data has a near-tied top-k boundary at
// magnitude ~0.46 (threshold 0.037) — rounds 3-6 proved ANY summation
// reassociation (split-K, Gram restructuring, MFMA multi-term splits)
// flips it and fails. Keep the serial k-ascending FMA chain.
#define TK 16
#define LDS_LD 132

__device__ __forceinline__ float soft_update(float oldv, float g) {
    float a = oldv + STEP_F * g;
    float m = fabsf(a) - THR_F;
    return m > 0.0f ? copysignf(m, a) : 0.0f;
}

// ---------------------------------------------------------------------------
// GEMM1: R = X - A*D.  A:[BATCH,DICT]  D:[DICT,EXP_DIM]  X,R:[BATCH,EXP_DIM]
// (byte-identical to round 7's verified kernel)
__global__ __launch_bounds__(256)
void gemm1_resid(const float* __restrict__ A, const float* __restrict__ D,
                 const float* __restrict__ X, float* __restrict__ R) {
    __shared__ float AsT[TK][LDS_LD];   // transposed A tile: [k][row]
    __shared__ float Bs [TK][LDS_LD];   // D tile straight:  [k][col]
    const int t  = threadIdx.x;
    const int tx = t & 15, ty = t >> 4;
    const int row0 = blockIdx.y * 128, col0 = blockIdx.x * 128;

    // A staging: thread t owns (row = t>>1, k-group = (t&1)*8)
    const int arow = t >> 1, akg = (t & 1) << 3;
    const float* pA = A + (size_t)(row0 + arow) * DICT + akg;
    // B staging: thread t owns (k-row = t>>4, col-group = (t&15)*8)
    const int bkr = t >> 4, bcg = (t & 15) << 3;
    const float* pB = D + (size_t)bkr * EXP_DIM + col0 + bcg;

    float acc[8][8] = {};

    for (int k0 = 0; k0 < DICT; k0 += TK) {
        float4 a0 = *(const float4*)(pA + k0);
        float4 a1 = *(const float4*)(pA + k0 + 4);
        float4 b0 = *(const float4*)(pB + (size_t)k0 * EXP_DIM);
        float4 b1 = *(const float4*)(pB + (size_t)k0 * EXP_DIM + 4);
        __syncthreads();
        AsT[akg + 0][arow] = a0.x; AsT[akg + 1][arow] = a0.y;
        AsT[akg + 2][arow] = a0.z; AsT[akg + 3][arow] = a0.w;
        AsT[akg + 4][arow] = a1.x; AsT[akg + 5][arow] = a1.y;
        AsT[akg + 6][arow] = a1.z; AsT[akg + 7][arow] = a1.w;
        *(float4*)&Bs[bkr][bcg]     = b0;
        *(float4*)&Bs[bkr][bcg + 4] = b1;
        __syncthreads();
#pragma unroll
        for (int k = 0; k < TK; ++k) {
            float4 av0 = *(const float4*)&AsT[k][ty * 4];
            float4 av1 = *(const float4*)&AsT[k][64 + ty * 4];
            float4 bv0 = *(const float4*)&Bs[k][tx * 4];
            float4 bv1 = *(const float4*)&Bs[k][64 + tx * 4];
            float av[8] = {av0.x, av0.y, av0.z, av0.w, av1.x, av1.y, av1.z, av1.w};
            float bv[8] = {bv0.x, bv0.y, bv0.z, bv0.w, bv1.x, bv1.y, bv1.z, bv1.w};
#pragma unroll
            for (int i = 0; i < 8; ++i)
#pragma unroll
                for (int j = 0; j < 8; ++j)
                    acc[i][j] += av[i] * bv[j];
        }
    }

#pragma unroll
    for (int i = 0; i < 8; ++i) {
        const int r = row0 + ((i < 4) ? (ty * 4 + i) : (64 + ty * 4 + i - 4));
        {
            const size_t off = (size_t)r * EXP_DIM + col0 + tx * 4;
            float4 xv = *(const float4*)&X[off];
            float4 o;
            o.x = xv.x - acc[i][0]; o.y = xv.y - acc[i][1];
            o.z = xv.z - acc[i][2]; o.w = xv.w - acc[i][3];
            *(float4*)&R[off] = o;
        }
        {
            const size_t off = (size_t)r * EXP_DIM + col0 + 64 + tx * 4;
            float4 xv = *(const float4*)&X[off];
            float4 o;
            o.x = xv.x - acc[i][4]; o.y = xv.y - acc[i][5];
            o.z = xv.z - acc[i][6]; o.w = xv.w - acc[i][7];
            *(float4*)&R[off] = o;
        }
    }
}

// ---------------------------------------------------------------------------
// GEMM2: A = soft(A + STEP * R*D^T).  R:[BATCH,EXP_DIM]  D:[DICT,EXP_DIM]
// (byte-identical to rounds 7/8/9/12/14 — measured ~83% of fp32 vector peak)
__global__ __launch_bounds__(256)
void gemm2_update(const float* __restrict__ Rsrc, const float* __restrict__ D,
                  float* __restrict__ Aa) {
    __shared__ float AsT[TK][LDS_LD];   // transposed R tile: [k][row]
    __shared__ float BsT[TK][LDS_LD];   // transposed D tile: [k][n]
    const int t  = threadIdx.x;
    const int tx = t & 15, ty = t >> 4;
    const int row0 = blockIdx.y * 128, col0 = blockIdx.x * 128;

    const int arow = t >> 1, akg = (t & 1) << 3;
    const float* pA = Rsrc + (size_t)(row0 + arow) * EXP_DIM + akg;
    const float* pB = D + (size_t)(col0 + arow) * EXP_DIM + akg;

    float acc[8][8] = {};

    for (int k0 = 0; k0 < EXP_DIM; k0 += TK) {
        float4 a0 = *(const float4*)(pA + k0);
        float4 a1 = *(const float4*)(pA + k0 + 4);
        float4 b0 = *(const float4*)(pB + k0);
        float4 b1 = *(const float4*)(pB + k0 + 4);
        __syncthreads();
        AsT[akg + 0][arow] = a0.x; AsT[akg + 1][arow] = a0.y;
        AsT[akg + 2][arow] = a0.z; AsT[akg + 3][arow] = a0.w;
        AsT[akg + 4][arow] = a1.x; AsT[akg + 5][arow] = a1.y;
        AsT[akg + 6][arow] = a1.z; AsT[akg + 7][arow] = a1.w;
        BsT[akg + 0][arow] = b0.x; BsT[akg + 1][arow] = b0.y;
        BsT[akg + 2][arow] = b0.z; BsT[akg + 3][arow] = b0.w;
        BsT[akg + 4][arow] = b1.x; BsT[akg + 5][arow] = b1.y;
        BsT[akg + 6][arow] = b1.z; BsT[akg + 7][arow] = b1.w;
        __syncthreads();
#pragma unroll
        for (int k = 0; k < TK; ++k) {
            float4 av0 = *(const float4*)&AsT[k][ty * 4];
            float4 av1 = *(const float4*)&AsT[k][64 + ty * 4];
            float4 bv0 = *(const float4*)&BsT[k][tx * 4];
            float4 bv1 = *(const float4*)&BsT[k][64 + tx * 4];
            float av[8] = {av0.x, av0.y, av0.z, av0.w, av1.x, av1.y, av1.z, av1.w};
            float bv[8] = {bv0.x, bv0.y, bv0.z, bv0.w, bv1.x, bv1.y, bv1.z, bv1.w};
#pragma unroll
            for (int i = 0; i < 8; ++i)
#pragma unroll
                for (int j = 0; j < 8; ++j)
                    acc[i][j] += av[i] * bv[j];
        }
    }

#pragma unroll
    for (int i = 0; i < 8; ++i) {
        const int r = row0 + ((i < 4) ? (ty * 4 + i) : (64 + ty * 4 + i - 4));
        {
            float4* p = (float4*)&Aa[(size_t)r * DICT + col0 + tx * 4];
            float4 oldv = *p;
            float4 o;
            o.x = soft_update(oldv.x, acc[i][0]);
            o.y = soft_update(oldv.y, acc[i][1]);
            o.z = soft_update(oldv.z, acc[i][2]);
            o.w = soft_update(oldv.w, acc[i][3]);
            *p = o;
        }
        {
            float4* p = (float4*)&Aa[(size_t)r * DICT + col0 + 64 + tx * 4];
            float4 oldv = *p;
            float4 o;
            o.x = soft_update(oldv.x, acc[i][4]);
            o.y = soft_update(oldv.y, acc[i][5]);
            o.z = soft_update(oldv.z, acc[i][6]);
            o.w = soft_update(oldv.w, acc[i][7]);
            *p = o;
        }
    }
}

// ---------------------------------------------------------------------------
// In-place top-KSP by |value| per row (exact MSB-first radix select; verified).
__global__ __launch_bounds__(256)
void topk_kernel(float* __restrict__ A) {
    const int row = blockIdx.x;
    float* a = A + (size_t)row * DICT;
    __shared__ unsigned int sb[DICT];
    __shared__ unsigned int hist[256];
    __shared__ unsigned int s_bin, s_need;
    const int t = threadIdx.x;

#pragma unroll
    for (int i = 0; i < DICT / 256; ++i) {
        int j = t + 256 * i;
        sb[j] = __float_as_uint(a[j]) & 0x7fffffffu;
    }

    unsigned int prefix = 0, needed = KSP;
    for (int shift = 24; shift >= 0; shift -= 8) {
        __syncthreads();
        hist[t] = 0;
        __syncthreads();
        unsigned int hmask = (shift == 24) ? 0u : (0xffffffffu << (shift + 8));
        for (int i = 0; i < DICT / 256; ++i) {
            unsigned int b = sb[t + 256 * i];
            if ((b & hmask) == prefix)
                atomicAdd(&hist[(b >> shift) & 0xffu], 1u);
        }
        __syncthreads();
        if (t == 0) {
            unsigned int cum = 0;
            for (int bin = 255; bin >= 0; --bin) {
                unsigned int h = hist[bin];
                if (cum + h >= needed) { s_bin = (unsigned int)bin; s_need = needed - cum; break; }
                cum += h;
            }
        }
        __syncthreads();
        prefix |= s_bin << shift;
        needed = s_need;
    }

    unsigned int E = hist[prefix & 0xffu];
    bool simple = (E == needed) || (prefix == 0);
    if (!simple) {
        if (t == 0) {
            unsigned int cnt = 0;
            for (int j = 0; j < DICT; ++j) {
                if (sb[j] == prefix) {
                    if (cnt < needed) sb[j] |= 0x80000000u;
                    ++cnt;
                }
            }
        }
        __syncthreads();
    }

    for (int i = 0; i < DICT / 256; ++i) {
        int j = t + 256 * i;
        unsigned int b = sb[j];
        bool keep = simple ? (b >= prefix)
                           : (((b & 0x7fffffffu) > prefix) || (b >> 31));
        float v = a[j];
        a[j] = keep ? v : 0.0f;
    }
}

// ---------------------------------------------------------------------------
extern "C" void kernel_launch(void* const* d_in, const int* in_sizes, int n_in,
                              void* d_out, int out_size, void* d_ws, size_t ws_size,
                              hipStream_t stream) {
    const float* X = (const float*)d_in[0];   // [8192,1024]
    const float* D = (const float*)d_in[1];   // [4096,1024]
    float* A = (float*)d_out;                 // [8192,4096] alpha, iterated in place
    float* R = (float*)d_ws;                  // [8192,1024] residual scratch (33.5 MB)

    hipMemsetAsync(A, 0, (size_t)BATCH * DICT * sizeof(float), stream);

    dim3 blk(256);
    dim3 g1(EXP_DIM / 128, BATCH / 128);  // 8 x 64 = 512 blocks
    dim3 g2(DICT / 128,    BATCH / 128);  // 32 x 64 = 2048 blocks

    // Iteration 0: A == 0 (memset), so gemm1 would compute R = X - 0 = X
    // bitwise. Skip it and feed X directly to gemm2 — trajectory-identical,
    // saves one full gemm1 dispatch (~990 us).
    hipLaunchKernelGGL(gemm2_update, g2, blk, 0, stream, X, D, A);
    for (int it = 1; it < NIT; ++it) {
        hipLaunchKernelGGL(gemm1_resid, g1, blk, 0, stream, A, D, X, R);
        hipLaunchKernelGGL(gemm2_update, g2, blk, 0, stream, R, D, A);
    }
    hipLaunchKernelGGL(topk_kernel, dim3(BATCH), blk, 0, stream, A);
}

// Round 16
// 30023.093 us; speedup vs baseline: 4.5666x; 1.0001x over previous
//
#include <hip/hip_runtime.h>
#include <math.h>

// Problem constants
#define BATCH   8192
#define EXP_DIM 1024
#define DICT    4096
#define NIT     20
#define KSP     409
#define STEP_F  0.1f
#define THR_F   0.01f

// Per-output summation is k strictly ascending, single fp32 accumulator
// (bit-identical trajectory to the verified rounds 0/7/8/9/14/15).
// HARD INVARIANT: the data has a near-tied top-k boundary at magnitude ~0.46
// (threshold 0.037) — rounds 3-6 proved ANY summation reassociation
// (split-K, Gram restructuring, MFMA multi-term splits) flips it and fails.
#define TK 16
#define LDS_LD 132
#define G1TK 32

__device__ __forceinline__ float soft_update(float oldv, float g) {
    float a = oldv + STEP_F * g;
    float m = fabsf(a) - THR_F;
    return m > 0.0f ? copysignf(m, a) : 0.0f;
}

// ---------------------------------------------------------------------------
// GEMM1: R = X - A*D.  A:[BATCH,DICT]  D:[DICT,EXP_DIM]  X,R:[BATCH,EXP_DIM]
// 128x128 tile, TK=32 (halved barriers vs round 7; 2x compute per staging
// round hides global-load latency), 8x8 micro-tile (16:1 FMA:ds_read_b128).
// k strictly ascending per output -> trajectory bit-identical.
__global__ __launch_bounds__(256)
void gemm1_resid(const float* __restrict__ A, const float* __restrict__ D,
                 const float* __restrict__ X, float* __restrict__ R) {
    __shared__ float AsT[G1TK][LDS_LD];   // transposed A tile: [k][row]
    __shared__ float Bs [G1TK][LDS_LD];   // D tile straight:  [k][col]
    const int t  = threadIdx.x;
    const int tx = t & 15, ty = t >> 4;
    const int row0 = blockIdx.y * 128, col0 = blockIdx.x * 128;

    // A staging: thread t owns (row = t>>1, k-half = (t&1)*16)  [16 floats]
    const int arow = t >> 1, akg = (t & 1) << 4;
    const float* pA = A + (size_t)(row0 + arow) * DICT + akg;
    // B staging: thread t owns k-rows (t>>4) and (t>>4)+16, col-group (t&15)*8
    const int bkr = t >> 4, bcg = (t & 15) << 3;
    const float* pB0 = D + (size_t)bkr * EXP_DIM + col0 + bcg;
    const float* pB1 = D + (size_t)(bkr + 16) * EXP_DIM + col0 + bcg;

    float acc[8][8] = {};

    for (int k0 = 0; k0 < DICT; k0 += G1TK) {
        float4 a0 = *(const float4*)(pA + k0);
        float4 a1 = *(const float4*)(pA + k0 + 4);
        float4 a2 = *(const float4*)(pA + k0 + 8);
        float4 a3 = *(const float4*)(pA + k0 + 12);
        float4 b0 = *(const float4*)(pB0 + (size_t)k0 * EXP_DIM);
        float4 b1 = *(const float4*)(pB0 + (size_t)k0 * EXP_DIM + 4);
        float4 b2 = *(const float4*)(pB1 + (size_t)k0 * EXP_DIM);
        float4 b3 = *(const float4*)(pB1 + (size_t)k0 * EXP_DIM + 4);
        __syncthreads();
        AsT[akg +  0][arow] = a0.x; AsT[akg +  1][arow] = a0.y;
        AsT[akg +  2][arow] = a0.z; AsT[akg +  3][arow] = a0.w;
        AsT[akg +  4][arow] = a1.x; AsT[akg +  5][arow] = a1.y;
        AsT[akg +  6][arow] = a1.z; AsT[akg +  7][arow] = a1.w;
        AsT[akg +  8][arow] = a2.x; AsT[akg +  9][arow] = a2.y;
        AsT[akg + 10][arow] = a2.z; AsT[akg + 11][arow] = a2.w;
        AsT[akg + 12][arow] = a3.x; AsT[akg + 13][arow] = a3.y;
        AsT[akg + 14][arow] = a3.z; AsT[akg + 15][arow] = a3.w;
        *(float4*)&Bs[bkr][bcg]          = b0;
        *(float4*)&Bs[bkr][bcg + 4]      = b1;
        *(float4*)&Bs[bkr + 16][bcg]     = b2;
        *(float4*)&Bs[bkr + 16][bcg + 4] = b3;
        __syncthreads();
#pragma unroll
        for (int k = 0; k < G1TK; ++k) {
            float4 av0 = *(const float4*)&AsT[k][ty * 4];
            float4 av1 = *(const float4*)&AsT[k][64 + ty * 4];
            float4 bv0 = *(const float4*)&Bs[k][tx * 4];
            float4 bv1 = *(const float4*)&Bs[k][64 + tx * 4];
            float av[8] = {av0.x, av0.y, av0.z, av0.w, av1.x, av1.y, av1.z, av1.w};
            float bv[8] = {bv0.x, bv0.y, bv0.z, bv0.w, bv1.x, bv1.y, bv1.z, bv1.w};
#pragma unroll
            for (int i = 0; i < 8; ++i)
#pragma unroll
                for (int j = 0; j < 8; ++j)
                    acc[i][j] += av[i] * bv[j];
        }
    }

#pragma unroll
    for (int i = 0; i < 8; ++i) {
        const int r = row0 + ((i < 4) ? (ty * 4 + i) : (64 + ty * 4 + i - 4));
        {
            const size_t off = (size_t)r * EXP_DIM + col0 + tx * 4;
            float4 xv = *(const float4*)&X[off];
            float4 o;
            o.x = xv.x - acc[i][0]; o.y = xv.y - acc[i][1];
            o.z = xv.z - acc[i][2]; o.w = xv.w - acc[i][3];
            *(float4*)&R[off] = o;
        }
        {
            const size_t off = (size_t)r * EXP_DIM + col0 + 64 + tx * 4;
            float4 xv = *(const float4*)&X[off];
            float4 o;
            o.x = xv.x - acc[i][4]; o.y = xv.y - acc[i][5];
            o.z = xv.z - acc[i][6]; o.w = xv.w - acc[i][7];
            *(float4*)&R[off] = o;
        }
    }
}

// ---------------------------------------------------------------------------
// GEMM2: A = soft(A + STEP * R*D^T).  R:[BATCH,EXP_DIM]  D:[DICT,EXP_DIM]
// (byte-identical to rounds 7/8/9/12/14/15 — measured ~83% of fp32 peak)
__global__ __launch_bounds__(256)
void gemm2_update(const float* __restrict__ Rsrc, const float* __restrict__ D,
                  float* __restrict__ Aa) {
    __shared__ float AsT[TK][LDS_LD];   // transposed R tile: [k][row]
    __shared__ float BsT[TK][LDS_LD];   // transposed D tile: [k][n]
    const int t  = threadIdx.x;
    const int tx = t & 15, ty = t >> 4;
    const int row0 = blockIdx.y * 128, col0 = blockIdx.x * 128;

    const int arow = t >> 1, akg = (t & 1) << 3;
    const float* pA = Rsrc + (size_t)(row0 + arow) * EXP_DIM + akg;
    const float* pB = D + (size_t)(col0 + arow) * EXP_DIM + akg;

    float acc[8][8] = {};

    for (int k0 = 0; k0 < EXP_DIM; k0 += TK) {
        float4 a0 = *(const float4*)(pA + k0);
        float4 a1 = *(const float4*)(pA + k0 + 4);
        float4 b0 = *(const float4*)(pB + k0);
        float4 b1 = *(const float4*)(pB + k0 + 4);
        __syncthreads();
        AsT[akg + 0][arow] = a0.x; AsT[akg + 1][arow] = a0.y;
        AsT[akg + 2][arow] = a0.z; AsT[akg + 3][arow] = a0.w;
        AsT[akg + 4][arow] = a1.x; AsT[akg + 5][arow] = a1.y;
        AsT[akg + 6][arow] = a1.z; AsT[akg + 7][arow] = a1.w;
        BsT[akg + 0][arow] = b0.x; BsT[akg + 1][arow] = b0.y;
        BsT[akg + 2][arow] = b0.z; BsT[akg + 3][arow] = b0.w;
        BsT[akg + 4][arow] = b1.x; BsT[akg + 5][arow] = b1.y;
        BsT[akg + 6][arow] = b1.z; BsT[akg + 7][arow] = b1.w;
        __syncthreads();
#pragma unroll
        for (int k = 0; k < TK; ++k) {
            float4 av0 = *(const float4*)&AsT[k][ty * 4];
            float4 av1 = *(const float4*)&AsT[k][64 + ty * 4];
            float4 bv0 = *(const float4*)&BsT[k][tx * 4];
            float4 bv1 = *(const float4*)&BsT[k][64 + tx * 4];
            float av[8] = {av0.x, av0.y, av0.z, av0.w, av1.x, av1.y, av1.z, av1.w};
            float bv[8] = {bv0.x, bv0.y, bv0.z, bv0.w, bv1.x, bv1.y, bv1.z, bv1.w};
#pragma unroll
            for (int i = 0; i < 8; ++i)
#pragma unroll
                for (int j = 0; j < 8; ++j)
                    acc[i][j] += av[i] * bv[j];
        }
    }

#pragma unroll
    for (int i = 0; i < 8; ++i) {
        const int r = row0 + ((i < 4) ? (ty * 4 + i) : (64 + ty * 4 + i - 4));
        {
            float4* p = (float4*)&Aa[(size_t)r * DICT + col0 + tx * 4];
            float4 oldv = *p;
            float4 o;
            o.x = soft_update(oldv.x, acc[i][0]);
            o.y = soft_update(oldv.y, acc[i][1]);
            o.z = soft_update(oldv.z, acc[i][2]);
            o.w = soft_update(oldv.w, acc[i][3]);
            *p = o;
        }
        {
            float4* p = (float4*)&Aa[(size_t)r * DICT + col0 + 64 + tx * 4];
            float4 oldv = *p;
            float4 o;
            o.x = soft_update(oldv.x, acc[i][4]);
            o.y = soft_update(oldv.y, acc[i][5]);
            o.z = soft_update(oldv.z, acc[i][6]);
            o.w = soft_update(oldv.w, acc[i][7]);
            *p = o;
        }
    }
}

// ---------------------------------------------------------------------------
// In-place top-KSP by |value| per row (exact MSB-first radix select; verified).
__global__ __launch_bounds__(256)
void topk_kernel(float* __restrict__ A) {
    const int row = blockIdx.x;
    float* a = A + (size_t)row * DICT;
    __shared__ unsigned int sb[DICT];
    __shared__ unsigned int hist[256];
    __shared__ unsigned int s_bin, s_need;
    const int t = threadIdx.x;

#pragma unroll
    for (int i = 0; i < DICT / 256; ++i) {
        int j = t + 256 * i;
        sb[j] = __float_as_uint(a[j]) & 0x7fffffffu;
    }

    unsigned int prefix = 0, needed = KSP;
    for (int shift = 24; shift >= 0; shift -= 8) {
        __syncthreads();
        hist[t] = 0;
        __syncthreads();
        unsigned int hmask = (shift == 24) ? 0u : (0xffffffffu << (shift + 8));
        for (int i = 0; i < DICT / 256; ++i) {
            unsigned int b = sb[t + 256 * i];
            if ((b & hmask) == prefix)
                atomicAdd(&hist[(b >> shift) & 0xffu], 1u);
        }
        __syncthreads();
        if (t == 0) {
            unsigned int cum = 0;
            for (int bin = 255; bin >= 0; --bin) {
                unsigned int h = hist[bin];
                if (cum + h >= needed) { s_bin = (unsigned int)bin; s_need = needed - cum; break; }
                cum += h;
            }
        }
        __syncthreads();
        prefix |= s_bin << shift;
        needed = s_need;
    }

    unsigned int E = hist[prefix & 0xffu];
    bool simple = (E == needed) || (prefix == 0);
    if (!simple) {
        if (t == 0) {
            unsigned int cnt = 0;
            for (int j = 0; j < DICT; ++j) {
                if (sb[j] == prefix) {
                    if (cnt < needed) sb[j] |= 0x80000000u;
                    ++cnt;
                }
            }
        }
        __syncthreads();
    }

    for (int i = 0; i < DICT / 256; ++i) {
        int j = t + 256 * i;
        unsigned int b = sb[j];
        bool keep = simple ? (b >= prefix)
                           : (((b & 0x7fffffffu) > prefix) || (b >> 31));
        float v = a[j];
        a[j] = keep ? v : 0.0f;
    }
}

// ---------------------------------------------------------------------------
extern "C" void kernel_launch(void* const* d_in, const int* in_sizes, int n_in,
                              void* d_out, int out_size, void* d_ws, size_t ws_size,
                              hipStream_t stream) {
    const float* X = (const float*)d_in[0];   // [8192,1024]
    const float* D = (const float*)d_in[1];   // [4096,1024]
    float* A = (float*)d_out;                 // [8192,4096] alpha, iterated in place
    float* R = (float*)d_ws;                  // [8192,1024] residual scratch (33.5 MB)

    hipMemsetAsync(A, 0, (size_t)BATCH * DICT * sizeof(float), stream);

    dim3 blk(256);
    dim3 g1(EXP_DIM / 128, BATCH / 128);  // 8 x 64 = 512 blocks
    dim3 g2(DICT / 128,    BATCH / 128);  // 32 x 64 = 2048 blocks

    // Iteration 0: A == 0 (memset), so gemm1 would compute R = X - 0 = X
    // bitwise. Skip it and feed X directly to gemm2 — trajectory-identical,
    // saves one full gemm1 dispatch (~990 us).
    hipLaunchKernelGGL(gemm2_update, g2, blk, 0, stream, X, D, A);
    for (int it = 1; it < NIT; ++it) {
        hipLaunchKernelGGL(gemm1_resid, g1, blk, 0, stream, A, D, X, R);
        hipLaunchKernelGGL(gemm2_update, g2, blk, 0, stream, R, D, A);
    }
    hipLaunchKernelGGL(topk_kernel, dim3(BATCH), blk, 0, stream, A);
}